// Round 10
// baseline (972.585 us; speedup 1.0000x reference)
//
#include <hip/hip_runtime.h>
#include <hip/hip_bf16.h>

// RNN scan via MFMA, latency-optimized. T=750 serial steps; per step
//   x = x + ALPHA*(-x + r@J^T + u@b_in^T + c_x + 0.1*n),  r = tanh(x)
// Block = 16 batches x 7 waves (wave w owns h-tile [16w,16w+16)), 64 blocks.
// J as static B-fragments in pinned VGPRs (hi/lo bf16). r exchanged per step
// via LDS in single bf16. Inputs prefetched 2 steps ahead in registers,
// VALUES asm-pinned + 256-VGPR budget (launch_bounds min-waves/EU=2) so the
// backend can neither sink nor remat the loads (R9 failure: VGPR=64 target
// sank prefetch to use -> ~900cyc HBM latency per step on the serial path).
// Induction pointers + immediate offsets replace per-step mad_u64 addressing.

typedef __attribute__((ext_vector_type(8))) short bf16x8;
typedef __attribute__((ext_vector_type(4))) float f32x4;

#define TSTEPS 750
#define BATCH  1024
#define HID    100
#define NT     7        // 7 h-tiles of 16 -> N=112 (cols 100..111 zero)
#define KT     4        // 4 k-tiles of 32 -> K=128 (k 100..127 zero)
#define KSTRIDE 136     // LDS row stride in bf16: 272B -> balanced 8-way b128 reads
#define THREADS (NT * 64)

constexpr float ALPHA = 0.1f;   // DT/TAU
constexpr float NSTD  = 0.1f;

__device__ __forceinline__ float ftanh(float x) {
    float e = __expf(2.0f * x);
    return 1.0f - 2.0f * __builtin_amdgcn_rcpf(e + 1.0f);
}

// round-to-nearest bf16 hi/lo split: v ~= hi + lo
__device__ __forceinline__ void bsplit(float v, unsigned& hi, unsigned& lo) {
    __hip_bfloat16 h = __float2bfloat16(v);
    unsigned hb = *reinterpret_cast<unsigned short*>(&h);
    float hf = __builtin_bit_cast(float, hb << 16);
    __hip_bfloat16 l = __float2bfloat16(v - hf);
    hi = hb;
    lo = *reinterpret_cast<unsigned short*>(&l);
}

#define PIN4(q) asm volatile("" : "+v"(q.x), "+v"(q.y), "+v"(q.z), "+v"(q.w));

__global__ void __launch_bounds__(THREADS, 2)   // min 2 waves/EU -> 256 VGPR budget
rnn_mfma_kernel(const float* __restrict__ input_seq,  // [T,B,4]
                const float* __restrict__ noise,      // [T,B,H]
                const float* __restrict__ J_w,        // [H,H]
                const float* __restrict__ b_in,       // [H,4]
                const float* __restrict__ c_x,        // [H]
                float* __restrict__ states)           // [T,B,H]
{
    const int tid = threadIdx.x;
    const int w   = tid >> 6;        // wave id = N-tile
    const int l   = tid & 63;
    const int lr  = l & 15;          // B/C col within tile; A batch-row
    const int lg  = l >> 4;          // lane group 0..3
    const int bid = blockIdx.x;      // batch tile (16 batches)

    const int  h    = w * 16 + lr;   // this lane's output h column
    const bool hval = (h < HID);
    const int  hc   = hval ? h : (HID - 1);

    // single bf16 r plane, double-buffered
    __shared__ __align__(16) unsigned short rB[2][16][KSTRIDE];
    for (int i = tid; i < 2 * 16 * KSTRIDE; i += THREADS)
        (&rB[0][0][0])[i] = 0;       // r(x0)=0; k>=100 stays 0 forever

    // ---- J B-fragments (verified layout: col=lane&15, k=(lane>>4)*8+j) ----
    int4 BH[KT], BL[KT];
#pragma unroll
    for (int t = 0; t < KT; ++t) {
        unsigned hs[8], ls[8];
#pragma unroll
        for (int j = 0; j < 8; ++j) {
            int k = 32 * t + 8 * lg + j;
            float v = (hval && k < HID) ? J_w[(size_t)hc * HID + k] : 0.0f;
            bsplit(v, hs[j], ls[j]);
        }
        BH[t] = make_int4((int)(hs[0] | (hs[1] << 16)), (int)(hs[2] | (hs[3] << 16)),
                          (int)(hs[4] | (hs[5] << 16)), (int)(hs[6] | (hs[7] << 16)));
        BL[t] = make_int4((int)(ls[0] | (ls[1] << 16)), (int)(ls[2] | (ls[3] << 16)),
                          (int)(ls[4] | (ls[5] << 16)), (int)(ls[6] | (ls[7] << 16)));
    }
    PIN4(BH[0]) PIN4(BH[1]) PIN4(BH[2]) PIN4(BH[3])
    PIN4(BL[0]) PIN4(BL[1]) PIN4(BL[2]) PIN4(BL[3])

    const float4 binp = *reinterpret_cast<const float4*>(b_in + (size_t)hc * 4);
    const float  cx   = c_x[hc];

    // x state: batch rows m = 4*lg + i (C layout: row=(lane>>4)*4+reg)
    f32x4 xv = {0.f, 0.f, 0.f, 0.f};

    // ---- induction pointers (per-i offsets are compile-time immediates) ----
    const int b0 = bid * 16 + 4 * lg;                 // lane's batch base
    const float* np = noise + (size_t)b0 * HID + hc;  // +i*HID (400B) per i
    const float* up = input_seq + (size_t)b0 * 4;     // +i*4   (16B)  per i
    float*       sp = states + (size_t)b0 * HID + h;  // +i*HID per i
    const size_t NSTEP = (size_t)BATCH * HID;         // noise/states t-stride
    const size_t USTEP = (size_t)BATCH * 4;

    // ---- 2-deep input prefetch (t=0, t=1), values pinned ----
    float4 uP0[4], uP1[4];
    float  nP0[4], nP1[4];
#pragma unroll
    for (int i = 0; i < 4; ++i) {
        nP0[i] = np[i * HID];
        uP0[i] = *reinterpret_cast<const float4*>(up + i * 4);
    }
    np += NSTEP; up += USTEP;
#pragma unroll
    for (int i = 0; i < 4; ++i) {
        nP1[i] = np[i * HID];
        uP1[i] = *reinterpret_cast<const float4*>(up + i * 4);
    }
    np += NSTEP; up += USTEP;     // now at t=2
    PIN4(uP0[0]) PIN4(uP0[1]) PIN4(uP0[2]) PIN4(uP0[3])
    PIN4(uP1[0]) PIN4(uP1[1]) PIN4(uP1[2]) PIN4(uP1[3])
    asm volatile("" : "+v"(nP0[0]), "+v"(nP0[1]), "+v"(nP0[2]), "+v"(nP0[3]));
    asm volatile("" : "+v"(nP1[0]), "+v"(nP1[1]), "+v"(nP1[2]), "+v"(nP1[3]));

    __syncthreads();   // LDS zero-init visible

    for (int t = 0; t < TSTEPS; ++t) {
        const int cur = t & 1, nxt = cur ^ 1;

        // 1. issue prefetch for t+2; raw barrier below does NOT drain vmcnt,
        //    so these stay in flight across ~2 steps. Pin values vs remat.
        float4 uP2[4];
        float  nP2[4];
#pragma unroll
        for (int i = 0; i < 4; ++i) {
            nP2[i] = np[i * HID];
            uP2[i] = *reinterpret_cast<const float4*>(up + i * 4);
        }
        PIN4(uP2[0]) PIN4(uP2[1]) PIN4(uP2[2]) PIN4(uP2[3])
        asm volatile("" : "+v"(nP2[0]), "+v"(nP2[1]), "+v"(nP2[2]), "+v"(nP2[3]));
        const bool adv = (t + 3 < TSTEPS);   // uniform -> scalar select
        np += adv ? NSTEP : 0;
        up += adv ? USTEP : 0;

        // 2. A-fragments of r from LDS (verified: row=lane&15, k=(lane>>4)*8+j)
        bf16x8 ar[KT];
#pragma unroll
        for (int kt = 0; kt < KT; ++kt)
            ar[kt] = *reinterpret_cast<const bf16x8*>(&rB[cur][lr][(4 * kt + lg) * 8]);

        // 3. e[i] = u.b_in + cx + NSTD*nz from landed prefetch regs
        float e[4];
#pragma unroll
        for (int i = 0; i < 4; ++i) {
            float t0 = __builtin_fmaf(NSTD, nP0[i], cx);
            t0 = __builtin_fmaf(uP0[i].x, binp.x, t0);
            t0 = __builtin_fmaf(uP0[i].y, binp.y, t0);
            t0 = __builtin_fmaf(uP0[i].z, binp.z, t0);
            e[i] = __builtin_fmaf(uP0[i].w, binp.w, t0);
        }

        // 4. MFMA: dot = r @ (Jhi + Jlo), two independent chains of 4
        f32x4 aA = {0.f, 0.f, 0.f, 0.f}, aB = aA;
#pragma unroll
        for (int kt = 0; kt < KT; ++kt) {
            aA = __builtin_amdgcn_mfma_f32_16x16x32_bf16(
                     ar[kt], __builtin_bit_cast(bf16x8, BH[kt]), aA, 0, 0, 0);
            aB = __builtin_amdgcn_mfma_f32_16x16x32_bf16(
                     ar[kt], __builtin_bit_cast(bf16x8, BL[kt]), aB, 0, 0, 0);
        }
        f32x4 dot = aA + aB;

        // 5. state update, states store, r_{t+1} pack+write
#pragma unroll
        for (int i = 0; i < 4; ++i) {
            float pre = dot[i] + e[i];
            float xn  = xv[i] + ALPHA * (pre - xv[i]);
            xv[i] = xn;
            if (hval) {
                sp[i * HID] = xn;
                __hip_bfloat16 rb = __float2bfloat16(ftanh(xn));
                rB[nxt][4 * lg + i][h] = *reinterpret_cast<unsigned short*>(&rb);
            }
        }
        sp += NSTEP;

        // 6. rotate prefetch registers
#pragma unroll
        for (int i = 0; i < 4; ++i) {
            uP0[i] = uP1[i]; uP1[i] = uP2[i];
            nP0[i] = nP1[i]; nP1[i] = nP2[i];
        }

        // 7. raw barrier: drain LDS only; global loads/stores stay in flight
        asm volatile("s_waitcnt lgkmcnt(0)" ::: "memory");
        __builtin_amdgcn_s_barrier();
        __builtin_amdgcn_sched_barrier(0);
    }
}

// Readout: out[b,0] = tanh(states[0,b,:]).wout + wb ; out[b,1] = same at T-1.
__global__ __launch_bounds__(64) void rnn_out_kernel(
    const float* __restrict__ states,
    const float* __restrict__ wout_w,
    const float* __restrict__ wout_b,
    float* __restrict__ out)
{
    const int b = blockIdx.x;
    const int l = threadIdx.x;
    const float* s0 = states + (size_t)b * HID;
    const float* sF = states + ((size_t)(TSTEPS - 1) * BATCH + b) * HID;

    float p0 = 0.f, pF = 0.f;
    if (l < HID) {
        p0 = ftanh(s0[l]) * wout_w[l];
        pF = ftanh(sF[l]) * wout_w[l];
    }
    const int l2 = l + 64;
    if (l2 < HID) {
        p0 += ftanh(s0[l2]) * wout_w[l2];
        pF += ftanh(sF[l2]) * wout_w[l2];
    }
#pragma unroll
    for (int off = 32; off > 0; off >>= 1) {
        p0 += __shfl_xor(p0, off, 64);
        pF += __shfl_xor(pF, off, 64);
    }
    if (l == 0) {
        const float wb = wout_b[0];
        out[b * 2 + 0] = p0 + wb;
        out[b * 2 + 1] = pF + wb;
    }
}

extern "C" void kernel_launch(void* const* d_in, const int* in_sizes, int n_in,
                              void* d_out, int out_size, void* d_ws, size_t ws_size,
                              hipStream_t stream) {
    const float* input_seq = (const float*)d_in[0];
    const float* noise     = (const float*)d_in[1];
    const float* J_w       = (const float*)d_in[2];
    const float* b_in      = (const float*)d_in[3];
    const float* c_x       = (const float*)d_in[4];
    const float* wout_w    = (const float*)d_in[5];
    const float* wout_b    = (const float*)d_in[6];

    float* out    = (float*)d_out;       // [B,2]
    float* states = out + 2 * BATCH;     // [T,B,H]

    rnn_mfma_kernel<<<BATCH / 16, THREADS, 0, stream>>>(
        input_seq, noise, J_w, b_in, c_x, states);
    rnn_out_kernel<<<BATCH, 64, 0, stream>>>(states, wout_w, wout_b, out);
}

// Round 11
// 808.757 us; speedup vs baseline: 1.2026x; 1.2026x over previous
//
#include <hip/hip_runtime.h>
#include <hip/hip_bf16.h>

// RNN scan via MFMA. T=750 serial steps; per step
//   x = x + ALPHA*(-x + r@J^T + u@b_in^T + c_x + 0.1*n),  r = tanh(x)
// Block = 16 batches x 7 waves (wave w owns h-tile [16w,16w+16)), 64 blocks.
// J as static B-fragments in pinned VGPRs (hi/lo bf16; one-time cost).
// r exchanged per step via LDS (single bf16).
// INPUTS staged via global_load_lds into triple-buffered LDS (zero register
// pressure -- R9/R10 showed the scheduler sinks/spills register prefetch).
// Pre-barrier wait is counted: vmcnt(4) leaves the 4 states-stores in
// flight but forces the (older) input prefetch to completion.

typedef __attribute__((ext_vector_type(8))) short bf16x8;
typedef __attribute__((ext_vector_type(4))) float f32x4;

#define TSTEPS 750
#define BATCH  1024
#define HID    100
#define NT     7        // 7 h-tiles of 16 -> N=112 (cols 100..111 zero)
#define KT     4        // 4 k-tiles of 32 -> K=128 (k 100..127 zero)
#define KSTRIDE 136     // rB row stride in bf16 (272B): balanced b128 banks
#define THREADS (NT * 64)

constexpr float ALPHA = 0.1f;   // DT/TAU
constexpr float NSTD  = 0.1f;

__device__ __forceinline__ float ftanh(float x) {
    float e = __expf(2.0f * x);
    return 1.0f - 2.0f * __builtin_amdgcn_rcpf(e + 1.0f);
}

// round-to-nearest bf16 hi/lo split: v ~= hi + lo
__device__ __forceinline__ void bsplit(float v, unsigned& hi, unsigned& lo) {
    __hip_bfloat16 h = __float2bfloat16(v);
    unsigned hb = *reinterpret_cast<unsigned short*>(&h);
    float hf = __builtin_bit_cast(float, hb << 16);
    __hip_bfloat16 l = __float2bfloat16(v - hf);
    hi = hb;
    lo = *reinterpret_cast<unsigned short*>(&l);
}

#define PIN4(q) asm volatile("" : "+v"(q.x), "+v"(q.y), "+v"(q.z), "+v"(q.w));

__global__ void __launch_bounds__(THREADS)
__attribute__((amdgpu_waves_per_eu(2, 2)))   // min=max=2: stop the 8-wave/EU squeeze
rnn_mfma_kernel(const float* __restrict__ input_seq,  // [T,B,4]
                const float* __restrict__ noise,      // [T,B,H]
                const float* __restrict__ J_w,        // [H,H]
                const float* __restrict__ b_in,       // [H,4]
                const float* __restrict__ c_x,        // [H]
                float* __restrict__ states)           // [T,B,H]
{
    const int tid = threadIdx.x;
    const int w   = tid >> 6;        // wave id = N-tile
    const int l   = tid & 63;
    const int lr  = l & 15;          // B/C col within tile; A batch-row
    const int lg  = l >> 4;          // lane group 0..3
    const int bid = blockIdx.x;      // batch tile (16 batches)

    const int  h    = w * 16 + lr;   // this lane's output h column
    const bool hval = (h < HID);
    const int  hc   = hval ? h : (HID - 1);

    __shared__ __align__(16) unsigned short rB[2][16][KSTRIDE]; // r (bf16), dbuf
    __shared__ __align__(16) float nbuf[3][16][HID];            // noise stage
    __shared__ __align__(16) float ubuf[3][16][4];              // u stage (after nbuf!)

    for (int i = tid; i < 2 * 16 * KSTRIDE; i += THREADS)
        (&rB[0][0][0])[i] = 0;       // r(x0)=0; k>=100 stays 0 forever

    // ---- J B-fragments (verified layout: col=lane&15, k=(lane>>4)*8+j) ----
    int4 BH[KT], BL[KT];
#pragma unroll
    for (int t = 0; t < KT; ++t) {
        unsigned hs[8], ls[8];
#pragma unroll
        for (int j = 0; j < 8; ++j) {
            int k = 32 * t + 8 * lg + j;
            float v = (hval && k < HID) ? J_w[(size_t)hc * HID + k] : 0.0f;
            bsplit(v, hs[j], ls[j]);
        }
        BH[t] = make_int4((int)(hs[0] | (hs[1] << 16)), (int)(hs[2] | (hs[3] << 16)),
                          (int)(hs[4] | (hs[5] << 16)), (int)(hs[6] | (hs[7] << 16)));
        BL[t] = make_int4((int)(ls[0] | (ls[1] << 16)), (int)(ls[2] | (ls[3] << 16)),
                          (int)(ls[4] | (ls[5] << 16)), (int)(ls[6] | (ls[7] << 16)));
    }
    PIN4(BH[0]) PIN4(BH[1]) PIN4(BH[2]) PIN4(BH[3])
    PIN4(BL[0]) PIN4(BL[1]) PIN4(BL[2]) PIN4(BL[3])

    const float4 binp = *reinterpret_cast<const float4*>(b_in + (size_t)hc * 4);
    const float  cx   = c_x[hc];

    f32x4 xv = {0.f, 0.f, 0.f, 0.f};   // x for batch rows m = 4*lg + i

    const size_t NSTEP = (size_t)BATCH * HID;
    const size_t USTEP = (size_t)BATCH * 4;
    const size_t nblk  = (size_t)bid * 16 * HID;   // block's noise offset within a step
    const size_t ublk  = (size_t)bid * 16 * 4;

    // ---- input staging: global_load_lds, 16B per lane ----
    // noise: 16 b x 100 h x 4B = 6400B = lanes 0..399, linear.
    // u:     16 b x 4 x 4B    =  256B = wave 6 lanes 16..31 (base -256B trick).
    auto PREFETCH = [&](int tt, int buf) {
        const float* nsrc = noise + (size_t)tt * NSTEP + nblk;
        const float* usrc = input_seq + (size_t)tt * USTEP + ublk;
        if (tid < 400) {
            __builtin_amdgcn_global_load_lds(
                (const __attribute__((address_space(1))) void*)(nsrc + tid * 4),
                (__attribute__((address_space(3))) void*)((float*)&nbuf[buf][0][0] + w * 256),
                16, 0, 0);
        } else if (tid < 416) {
            __builtin_amdgcn_global_load_lds(
                (const __attribute__((address_space(1))) void*)(usrc + (tid - 400) * 4),
                (__attribute__((address_space(3))) void*)((float*)&ubuf[buf][0][0] - 64),
                16, 0, 0);
        }
    };

    float* sp = states + (size_t)(bid * 16 + 4 * lg) * HID + h;   // + i*HID, + t*NSTEP

    PREFETCH(0, 0);
    PREFETCH(1, 1);
    __syncthreads();   // drains vmcnt+lgkmcnt once (prologue only)

    int cur3 = 0, pf3 = 2;
    for (int t = 0; t < TSTEPS; ++t) {
        const int cur = t & 1, nxt = cur ^ 1;

        // 1. issue prefetch for t+2 into buffer (t+2)%3. Its previous readers
        //    finished before the t-1 barrier; in flight ~2 steps.
        const int tt = (t + 2 < TSTEPS) ? (t + 2) : (TSTEPS - 1);
        PREFETCH(tt, pf3);

        // 2. A-fragments of r from LDS (row=lane&15, k=(lane>>4)*8+j)
        bf16x8 ar[KT];
#pragma unroll
        for (int kt = 0; kt < KT; ++kt)
            ar[kt] = *reinterpret_cast<const bf16x8*>(&rB[cur][lr][(4 * kt + lg) * 8]);

        // 3. e[i] = u.b_in + cx + NSTD*nz from staged LDS
        //    u read is wave-uniform per i -> broadcast; noise b32 2-way max.
        float e[4];
#pragma unroll
        for (int i = 0; i < 4; ++i) {
            float4 uu = *reinterpret_cast<const float4*>(&ubuf[cur3][4 * lg + i][0]);
            float nz  = nbuf[cur3][4 * lg + i][hc];
            float t0 = __builtin_fmaf(NSTD, nz, cx);
            t0 = __builtin_fmaf(uu.x, binp.x, t0);
            t0 = __builtin_fmaf(uu.y, binp.y, t0);
            t0 = __builtin_fmaf(uu.z, binp.z, t0);
            e[i] = __builtin_fmaf(uu.w, binp.w, t0);
        }

        // 4. MFMA: dot = r @ (Jhi + Jlo), two independent chains of 4
        f32x4 aA = {0.f, 0.f, 0.f, 0.f}, aB = aA;
#pragma unroll
        for (int kt = 0; kt < KT; ++kt) {
            aA = __builtin_amdgcn_mfma_f32_16x16x32_bf16(
                     ar[kt], __builtin_bit_cast(bf16x8, BH[kt]), aA, 0, 0, 0);
            aB = __builtin_amdgcn_mfma_f32_16x16x32_bf16(
                     ar[kt], __builtin_bit_cast(bf16x8, BL[kt]), aB, 0, 0, 0);
        }
        f32x4 dot = aA + aB;

        // 5. state update, states store (4 vmem, left in flight), r pack+write
#pragma unroll
        for (int i = 0; i < 4; ++i) {
            float pre = dot[i] + e[i];
            float xn  = xv[i] + ALPHA * (pre - xv[i]);
            xv[i] = xn;
            if (hval) {
                sp[i * HID] = xn;
                __hip_bfloat16 rb = __float2bfloat16(ftanh(xn));
                rB[nxt][4 * lg + i][h] = *reinterpret_cast<unsigned short*>(&rb);
            }
        }
        sp += NSTEP;

        // 6. rotate staging buffer indices (uniform scalar selects)
        cur3 = (cur3 == 2) ? 0 : cur3 + 1;
        pf3  = (pf3 == 2) ? 0 : pf3 + 1;

        // 7. counted wait: rB writes visible (lgkmcnt 0); input prefetch
        //    complete (vmcnt<=4 forces the pre-store gl_lds ops done) while
        //    the 4 states stores stay in flight.
        asm volatile("s_waitcnt vmcnt(4) lgkmcnt(0)" ::: "memory");
        __builtin_amdgcn_s_barrier();
        __builtin_amdgcn_sched_barrier(0);
    }
}

// Readout: out[b,0] = tanh(states[0,b,:]).wout + wb ; out[b,1] = same at T-1.
__global__ __launch_bounds__(64) void rnn_out_kernel(
    const float* __restrict__ states,
    const float* __restrict__ wout_w,
    const float* __restrict__ wout_b,
    float* __restrict__ out)
{
    const int b = blockIdx.x;
    const int l = threadIdx.x;
    const float* s0 = states + (size_t)b * HID;
    const float* sF = states + ((size_t)(TSTEPS - 1) * BATCH + b) * HID;

    float p0 = 0.f, pF = 0.f;
    if (l < HID) {
        p0 = ftanh(s0[l]) * wout_w[l];
        pF = ftanh(sF[l]) * wout_w[l];
    }
    const int l2 = l + 64;
    if (l2 < HID) {
        p0 += ftanh(s0[l2]) * wout_w[l2];
        pF += ftanh(sF[l2]) * wout_w[l2];
    }
#pragma unroll
    for (int off = 32; off > 0; off >>= 1) {
        p0 += __shfl_xor(p0, off, 64);
        pF += __shfl_xor(pF, off, 64);
    }
    if (l == 0) {
        const float wb = wout_b[0];
        out[b * 2 + 0] = p0 + wb;
        out[b * 2 + 1] = pF + wb;
    }
}

extern "C" void kernel_launch(void* const* d_in, const int* in_sizes, int n_in,
                              void* d_out, int out_size, void* d_ws, size_t ws_size,
                              hipStream_t stream) {
    const float* input_seq = (const float*)d_in[0];
    const float* noise     = (const float*)d_in[1];
    const float* J_w       = (const float*)d_in[2];
    const float* b_in      = (const float*)d_in[3];
    const float* c_x       = (const float*)d_in[4];
    const float* wout_w    = (const float*)d_in[5];
    const float* wout_b    = (const float*)d_in[6];

    float* out    = (float*)d_out;       // [B,2]
    float* states = out + 2 * BATCH;     // [T,B,H]

    rnn_mfma_kernel<<<BATCH / 16, THREADS, 0, stream>>>(
        input_seq, noise, J_w, b_in, c_x, states);
    rnn_out_kernel<<<BATCH, 64, 0, stream>>>(states, wout_w, wout_b, out);
}